// Round 1
// baseline (548.385 us; speedup 1.0000x reference)
//
#include <hip/hip_runtime.h>
#include <hip/hip_bf16.h>

#define B_   4
#define C_   256
#define HH   48
#define WW   48
#define L_   2304
#define BL   9216
#define CE_  512
#define NS   16
#define DTR  32
#define NCH  18
#define CHL  128

// ---------------- LayerNorm (per-pixel over C=256 channels) ----------------
__global__ __launch_bounds__(256) void ln_k(const float* __restrict__ x,
                                            const float* __restrict__ w,
                                            const float* __restrict__ bia,
                                            float* __restrict__ xn) {
  int p = blockIdx.x;                 // 0..BL-1
  int b = p / L_, q = p - b * L_;
  int c = threadIdx.x;                // 256 threads
  float val = x[((size_t)(b * C_ + c)) * L_ + q];
  float s = val, s2 = val * val;
  #pragma unroll
  for (int off = 32; off >= 1; off >>= 1) {
    s  += __shfl_down(s, off);
    s2 += __shfl_down(s2, off);
  }
  __shared__ float ws[4], ws2[4];
  int wid = threadIdx.x >> 6, lane = threadIdx.x & 63;
  if (lane == 0) { ws[wid] = s; ws2[wid] = s2; }
  __syncthreads();
  float ts  = ws[0] + ws[1] + ws[2] + ws[3];
  float ts2 = ws2[0] + ws2[1] + ws2[2] + ws2[3];
  float mu  = ts * (1.f / C_);
  float var = ts2 * (1.f / C_) - mu * mu;
  float r   = rsqrtf(var + 1e-6f);
  xn[(size_t)p * C_ + c] = (val - mu) * r * w[c] + bia[c];
}

// ---------------- shared fp32 GEMM core: C[64x64] = A @ B^T ----------------
// A: M x K row-major (lda), B: N x K row-major (ldb). 256 threads, 4x4/thread.
__device__ __forceinline__ void gemm64(const float* __restrict__ A, int lda,
                                       const float* __restrict__ Bm, int ldb,
                                       int K, int m0, int n0, float acc[4][4]) {
  __shared__ float As[16][64];
  __shared__ float Bs[16][64];
  const int tid = threadIdx.x;
  const int tx = tid & 15, ty = tid >> 4;
  const int lrow = tid >> 2;          // 0..63
  const int lk   = (tid & 3) << 2;    // 0,4,8,12
  #pragma unroll
  for (int i = 0; i < 4; i++)
    #pragma unroll
    for (int j = 0; j < 4; j++) acc[i][j] = 0.f;
  for (int k0 = 0; k0 < K; k0 += 16) {
    float4 av = *(const float4*)(A  + (size_t)(m0 + lrow) * lda + k0 + lk);
    float4 bv = *(const float4*)(Bm + (size_t)(n0 + lrow) * ldb + k0 + lk);
    __syncthreads();
    As[lk + 0][lrow] = av.x; As[lk + 1][lrow] = av.y;
    As[lk + 2][lrow] = av.z; As[lk + 3][lrow] = av.w;
    Bs[lk + 0][lrow] = bv.x; Bs[lk + 1][lrow] = bv.y;
    Bs[lk + 2][lrow] = bv.z; Bs[lk + 3][lrow] = bv.w;
    __syncthreads();
    #pragma unroll
    for (int kk = 0; kk < 16; kk++) {
      float4 a4 = *(const float4*)&As[kk][ty << 2];
      float4 b4 = *(const float4*)&Bs[kk][tx << 2];
      float a[4]  = {a4.x, a4.y, a4.z, a4.w};
      float bb[4] = {b4.x, b4.y, b4.z, b4.w};
      #pragma unroll
      for (int i = 0; i < 4; i++)
        #pragma unroll
        for (int j = 0; j < 4; j++) acc[i][j] = fmaf(a[i], bb[j], acc[i][j]);
    }
  }
}

// ---------------- expand GEMM: uv = xn @ w_ex^T + b_ex; store u, v ----------
__global__ __launch_bounds__(256) void gemm_expand_k(const float* __restrict__ xn,
                                                     const float* __restrict__ w_ex,
                                                     const float* __restrict__ b_ex,
                                                     float* __restrict__ u,
                                                     float* __restrict__ vraw) {
  float acc[4][4];
  int m0 = blockIdx.y * 64, n0 = blockIdx.x * 64;
  gemm64(xn, C_, w_ex, C_, C_, m0, n0, acc);
  int tx = threadIdx.x & 15, ty = threadIdx.x >> 4;
  #pragma unroll
  for (int i = 0; i < 4; i++)
    #pragma unroll
    for (int j = 0; j < 4; j++) {
      int m = m0 + (ty << 2) + i, n = n0 + (tx << 2) + j;
      float val = acc[i][j] + b_ex[n];
      if (n < CE_) u[(size_t)m * CE_ + n] = val;
      else         vraw[(size_t)m * CE_ + (n - CE_)] = val;
    }
}

// ---------------- depthwise 3x3 conv (SAME) + SiLU -------------------------
__global__ __launch_bounds__(256) void dwconv_k(const float* __restrict__ vraw,
                                                const float* __restrict__ kw,
                                                float* __restrict__ vs) {
  int p = blockIdx.x;
  int b = p / L_, q = p - b * L_;
  int y = q / WW, x = q - y * WW;
  for (int cc = threadIdx.x; cc < CE_; cc += 256) {
    float acc = 0.f;
    #pragma unroll
    for (int ky = 0; ky < 3; ky++) {
      int yy = y + ky - 1;
      if (yy < 0 || yy >= HH) continue;
      #pragma unroll
      for (int kx = 0; kx < 3; kx++) {
        int xx = x + kx - 1;
        if (xx < 0 || xx >= WW) continue;
        acc += vraw[((size_t)(b * L_ + yy * WW + xx)) * CE_ + cc] * kw[(ky * 3 + kx) * CE_ + cc];
      }
    }
    float s = 1.f / (1.f + expf(-acc));
    vs[(size_t)p * CE_ + cc] = acc * s;
  }
}

// ---------------- x-proj GEMM: dbc = vs @ W_xproj^T + b_xproj ---------------
__global__ __launch_bounds__(256) void gemm_xproj_k(const float* __restrict__ vs,
                                                    const float* __restrict__ Wxp,
                                                    const float* __restrict__ bxp,
                                                    float* __restrict__ dbc) {
  float acc[4][4];
  int m0 = blockIdx.y * 64, n0 = blockIdx.x * 64;   // n0 == 0
  gemm64(vs, CE_, Wxp, CE_, CE_, m0, n0, acc);
  int tx = threadIdx.x & 15, ty = threadIdx.x >> 4;
  #pragma unroll
  for (int i = 0; i < 4; i++)
    #pragma unroll
    for (int j = 0; j < 4; j++) {
      int m = m0 + (ty << 2) + i, n = n0 + (tx << 2) + j;
      dbc[(size_t)m * 64 + n] = acc[i][j] + bxp[n];
    }
}

// ---------------- dt GEMM + softplus: delta = sp(dt @ W_dt^T + b_dt) --------
__global__ __launch_bounds__(256) void gemm_dt_k(const float* __restrict__ dbc,
                                                 const float* __restrict__ Wdt,
                                                 const float* __restrict__ bdt,
                                                 float* __restrict__ delta) {
  float acc[4][4];
  int m0 = blockIdx.y * 64, n0 = blockIdx.x * 64;
  gemm64(dbc, 64, Wdt, DTR, DTR, m0, n0, acc);
  int tx = threadIdx.x & 15, ty = threadIdx.x >> 4;
  #pragma unroll
  for (int i = 0; i < 4; i++)
    #pragma unroll
    for (int j = 0; j < 4; j++) {
      int m = m0 + (ty << 2) + i, n = n0 + (tx << 2) + j;
      float xv = acc[i][j] + bdt[n];
      delta[(size_t)m * CE_ + n] = (xv > 20.f) ? xv : log1pf(expf(xv));
    }
}

// ---------------- scan phase1: per-chunk partial state + delta-sum ----------
__global__ __launch_bounds__(256) void scan1_k(const float* __restrict__ delta,
                                               const float* __restrict__ dbc,
                                               const float* __restrict__ vs,
                                               const float* __restrict__ A_log,
                                               float* __restrict__ S,
                                               float* __restrict__ Dsum) {
  int b = blockIdx.z, ch = blockIdx.y, c0 = blockIdx.x << 4;
  int tid = threadIdx.x;
  int n = tid & 15, ci = tid >> 4;
  int c = c0 + ci;
  float Ac = -expf(A_log[c * NS + n]);
  float h = 0.f, dsum = 0.f;
  int mbase = b * L_ + ch * CHL;
  for (int t = 0; t < CHL; t++) {
    int m = mbase + t;
    float d  = delta[(size_t)m * CE_ + c];
    float bt = dbc[(size_t)m * 64 + DTR + n];
    float vv = vs[(size_t)m * CE_ + c];
    h = fmaf(h, expf(d * Ac), d * bt * vv);
    dsum += d;
  }
  int sidx = (b * NCH + ch) * CE_ + c;
  S[(size_t)sidx * NS + n] = h;
  if (n == 0) Dsum[sidx] = dsum;
}

// ---------------- scan phase2: compose chunk boundaries ---------------------
__global__ __launch_bounds__(256) void scan2_k(const float* __restrict__ A_log,
                                               const float* __restrict__ S,
                                               const float* __restrict__ Dsum,
                                               float* __restrict__ hstart) {
  int idx = blockIdx.x * 256 + threadIdx.x;   // 32768 total
  int n = idx & 15, c = (idx >> 4) & 511, b = idx >> 13;
  float Ac = -expf(A_log[c * NS + n]);
  float h = 0.f;
  for (int ch = 0; ch < NCH; ch++) {
    int sidx = (b * NCH + ch) * CE_ + c;
    hstart[(size_t)sidx * NS + n] = h;
    h = fmaf(h, expf(Ac * Dsum[sidx]), S[(size_t)sidx * NS + n]);
  }
}

// ---------------- scan phase3: replay with h_start, y, fused z --------------
// z = y*g + gate = u * (y*sigmoid(u) + v_silu*sigmoid(-u))
__global__ __launch_bounds__(256) void scan3_k(const float* __restrict__ delta,
                                               const float* __restrict__ dbc,
                                               const float* __restrict__ vs,
                                               const float* __restrict__ A_log,
                                               const float* __restrict__ Dv,
                                               const float* __restrict__ hstart,
                                               const float* __restrict__ u,
                                               float* __restrict__ z) {
  int b = blockIdx.z, ch = blockIdx.y, c0 = blockIdx.x << 4;
  int tid = threadIdx.x;
  int n = tid & 15, ci = tid >> 4;
  int c = c0 + ci;
  float Ac = -expf(A_log[c * NS + n]);
  int sidx = (b * NCH + ch) * CE_ + c;
  float h  = hstart[(size_t)sidx * NS + n];
  float Dc = Dv[c];
  int mbase = b * L_ + ch * CHL;
  for (int t = 0; t < CHL; t++) {
    int m = mbase + t;
    float d  = delta[(size_t)m * CE_ + c];
    float bt = dbc[(size_t)m * 64 + DTR + n];
    float ct = dbc[(size_t)m * 64 + DTR + NS + n];
    float vv = vs[(size_t)m * CE_ + c];
    h = fmaf(h, expf(d * Ac), d * bt * vv);
    float yp = h * ct;
    yp += __shfl_xor(yp, 1, 16);
    yp += __shfl_xor(yp, 2, 16);
    yp += __shfl_xor(yp, 4, 16);
    yp += __shfl_xor(yp, 8, 16);
    if (n == 0) {
      float yv = yp + Dc * vv;
      float uu = u[(size_t)m * CE_ + c];
      float s  = 1.f / (1.f + expf(-uu));
      z[(size_t)m * CE_ + c] = uu * (yv * s + vv * (1.f - s));
    }
  }
}

// ---------------- out-proj GEMM + NCHW transpose ----------------------------
__global__ __launch_bounds__(256) void gemm_proj_k(const float* __restrict__ z,
                                                   const float* __restrict__ w_proj,
                                                   const float* __restrict__ b_proj,
                                                   float* __restrict__ out) {
  float acc[4][4];
  int m0 = blockIdx.y * 64, n0 = blockIdx.x * 64;
  gemm64(z, CE_, w_proj, CE_, CE_, m0, n0, acc);
  int tx = threadIdx.x & 15, ty = threadIdx.x >> 4;
  #pragma unroll
  for (int i = 0; i < 4; i++)
    #pragma unroll
    for (int j = 0; j < 4; j++) {
      int m = m0 + (ty << 2) + i, n = n0 + (tx << 2) + j;
      int b = m / L_, p = m - b * L_;
      out[((size_t)(b * C_ + n)) * L_ + p] = acc[i][j] + b_proj[n];
    }
}

extern "C" void kernel_launch(void* const* d_in, const int* in_sizes, int n_in,
                              void* d_out, int out_size, void* d_ws, size_t ws_size,
                              hipStream_t stream) {
  const float* x      = (const float*)d_in[0];
  const float* norm_w = (const float*)d_in[1];
  const float* norm_b = (const float*)d_in[2];
  const float* w_ex   = (const float*)d_in[3];
  const float* b_ex   = (const float*)d_in[4];
  const float* w_proj = (const float*)d_in[5];
  const float* b_proj = (const float*)d_in[6];
  const float* dw_k   = (const float*)d_in[7];
  const float* A_log  = (const float*)d_in[8];
  const float* Dv     = (const float*)d_in[9];
  const float* W_xp   = (const float*)d_in[10];
  const float* b_xp   = (const float*)d_in[11];
  const float* W_dt   = (const float*)d_in[12];
  const float* b_dt   = (const float*)d_in[13];
  float* out = (float*)d_out;

  float* ws = (float*)d_ws;
  float* u      = ws;                          // BL*CE
  float* vraw   = u      + (size_t)BL * CE_;   // BL*CE  (reused as z)
  float* vs     = vraw   + (size_t)BL * CE_;   // BL*CE
  float* delta  = vs     + (size_t)BL * CE_;   // BL*CE
  float* dbc    = delta  + (size_t)BL * CE_;   // BL*64
  float* S      = dbc    + (size_t)BL * 64;    // B*NCH*CE*NS
  float* Dsum   = S      + (size_t)B_ * NCH * CE_ * NS;  // B*NCH*CE
  float* hstart = Dsum   + (size_t)B_ * NCH * CE_;       // B*NCH*CE*NS
  float* xn = out;      // borrow output buffer for xn (exact size match)
  float* z  = vraw;

  ln_k<<<BL, 256, 0, stream>>>(x, norm_w, norm_b, xn);
  gemm_expand_k<<<dim3(16, 144), 256, 0, stream>>>(xn, w_ex, b_ex, u, vraw);
  dwconv_k<<<BL, 256, 0, stream>>>(vraw, dw_k, vs);
  gemm_xproj_k<<<dim3(1, 144), 256, 0, stream>>>(vs, W_xp, b_xp, dbc);
  gemm_dt_k<<<dim3(8, 144), 256, 0, stream>>>(dbc, W_dt, b_dt, delta);
  scan1_k<<<dim3(32, NCH, B_), 256, 0, stream>>>(delta, dbc, vs, A_log, S, Dsum);
  scan2_k<<<128, 256, 0, stream>>>(A_log, S, Dsum, hstart);
  scan3_k<<<dim3(32, NCH, B_), 256, 0, stream>>>(delta, dbc, vs, A_log, Dv, hstart, u, z);
  gemm_proj_k<<<dim3(4, 144), 256, 0, stream>>>(z, w_proj, b_proj, out);
}

// Round 2
// 391.521 us; speedup vs baseline: 1.4007x; 1.4007x over previous
//
#include <hip/hip_runtime.h>
#include <hip/hip_bf16.h>

#define B_   4
#define C_   256
#define HH   48
#define WW   48
#define L_   2304
#define BL   9216
#define CE_  512
#define NS   16
#define DTR  32
#define NCH  36
#define CHL  64

// ---------------- LayerNorm (per-pixel over C=256 channels) ----------------
__global__ __launch_bounds__(256) void ln_k(const float* __restrict__ x,
                                            const float* __restrict__ w,
                                            const float* __restrict__ bia,
                                            float* __restrict__ xn) {
  int p = blockIdx.x;                 // 0..BL-1
  int b = p / L_, q = p - b * L_;
  int c = threadIdx.x;                // 256 threads
  float val = x[((size_t)(b * C_ + c)) * L_ + q];
  float s = val, s2 = val * val;
  #pragma unroll
  for (int off = 32; off >= 1; off >>= 1) {
    s  += __shfl_down(s, off);
    s2 += __shfl_down(s2, off);
  }
  __shared__ float ws[4], ws2[4];
  int wid = threadIdx.x >> 6, lane = threadIdx.x & 63;
  if (lane == 0) { ws[wid] = s; ws2[wid] = s2; }
  __syncthreads();
  float ts  = ws[0] + ws[1] + ws[2] + ws[3];
  float ts2 = ws2[0] + ws2[1] + ws2[2] + ws2[3];
  float mu  = ts * (1.f / C_);
  float var = ts2 * (1.f / C_) - mu * mu;
  float r   = rsqrtf(var + 1e-6f);
  xn[(size_t)p * C_ + c] = (val - mu) * r * w[c] + bia[c];
}

// ---------------- shared fp32 GEMM core: C[64x64] = A @ B^T ----------------
__device__ __forceinline__ void gemm64(const float* __restrict__ A, int lda,
                                       const float* __restrict__ Bm, int ldb,
                                       int K, int m0, int n0, float acc[4][4]) {
  __shared__ float As[16][64];
  __shared__ float Bs[16][64];
  const int tid = threadIdx.x;
  const int tx = tid & 15, ty = tid >> 4;
  const int lrow = tid >> 2;          // 0..63
  const int lk   = (tid & 3) << 2;    // 0,4,8,12
  #pragma unroll
  for (int i = 0; i < 4; i++)
    #pragma unroll
    for (int j = 0; j < 4; j++) acc[i][j] = 0.f;
  for (int k0 = 0; k0 < K; k0 += 16) {
    float4 av = *(const float4*)(A  + (size_t)(m0 + lrow) * lda + k0 + lk);
    float4 bv = *(const float4*)(Bm + (size_t)(n0 + lrow) * ldb + k0 + lk);
    __syncthreads();
    As[lk + 0][lrow] = av.x; As[lk + 1][lrow] = av.y;
    As[lk + 2][lrow] = av.z; As[lk + 3][lrow] = av.w;
    Bs[lk + 0][lrow] = bv.x; Bs[lk + 1][lrow] = bv.y;
    Bs[lk + 2][lrow] = bv.z; Bs[lk + 3][lrow] = bv.w;
    __syncthreads();
    #pragma unroll
    for (int kk = 0; kk < 16; kk++) {
      float4 a4 = *(const float4*)&As[kk][ty << 2];
      float4 b4 = *(const float4*)&Bs[kk][tx << 2];
      float a[4]  = {a4.x, a4.y, a4.z, a4.w};
      float bb[4] = {b4.x, b4.y, b4.z, b4.w};
      #pragma unroll
      for (int i = 0; i < 4; i++)
        #pragma unroll
        for (int j = 0; j < 4; j++) acc[i][j] = fmaf(a[i], bb[j], acc[i][j]);
    }
  }
}

// ---------------- expand GEMM: uv = xn @ w_ex^T + b_ex; store u, v ----------
__global__ __launch_bounds__(256) void gemm_expand_k(const float* __restrict__ xn,
                                                     const float* __restrict__ w_ex,
                                                     const float* __restrict__ b_ex,
                                                     float* __restrict__ u,
                                                     float* __restrict__ vraw) {
  float acc[4][4];
  int m0 = blockIdx.y * 64, n0 = blockIdx.x * 64;
  gemm64(xn, C_, w_ex, C_, C_, m0, n0, acc);
  int tx = threadIdx.x & 15, ty = threadIdx.x >> 4;
  #pragma unroll
  for (int i = 0; i < 4; i++)
    #pragma unroll
    for (int j = 0; j < 4; j++) {
      int m = m0 + (ty << 2) + i, n = n0 + (tx << 2) + j;
      float val = acc[i][j] + b_ex[n];
      if (n < CE_) u[(size_t)m * CE_ + n] = val;
      else         vraw[(size_t)m * CE_ + (n - CE_)] = val;
    }
}

// ---------------- depthwise 3x3 conv (SAME) + SiLU -------------------------
__global__ __launch_bounds__(256) void dwconv_k(const float* __restrict__ vraw,
                                                const float* __restrict__ kw,
                                                float* __restrict__ vs) {
  int p = blockIdx.x;
  int b = p / L_, q = p - b * L_;
  int y = q / WW, x = q - y * WW;
  for (int cc = threadIdx.x; cc < CE_; cc += 256) {
    float acc = 0.f;
    #pragma unroll
    for (int ky = 0; ky < 3; ky++) {
      int yy = y + ky - 1;
      if (yy < 0 || yy >= HH) continue;
      #pragma unroll
      for (int kx = 0; kx < 3; kx++) {
        int xx = x + kx - 1;
        if (xx < 0 || xx >= WW) continue;
        acc += vraw[((size_t)(b * L_ + yy * WW + xx)) * CE_ + cc] * kw[(ky * 3 + kx) * CE_ + cc];
      }
    }
    float s = 1.f / (1.f + __expf(-acc));
    vs[(size_t)p * CE_ + cc] = acc * s;
  }
}

// ---------------- x-proj GEMM: dbc = vs @ W_xproj^T + b_xproj ---------------
__global__ __launch_bounds__(256) void gemm_xproj_k(const float* __restrict__ vs,
                                                    const float* __restrict__ Wxp,
                                                    const float* __restrict__ bxp,
                                                    float* __restrict__ dbc) {
  float acc[4][4];
  int m0 = blockIdx.y * 64, n0 = blockIdx.x * 64;   // n0 == 0
  gemm64(vs, CE_, Wxp, CE_, CE_, m0, n0, acc);
  int tx = threadIdx.x & 15, ty = threadIdx.x >> 4;
  #pragma unroll
  for (int i = 0; i < 4; i++)
    #pragma unroll
    for (int j = 0; j < 4; j++) {
      int m = m0 + (ty << 2) + i, n = n0 + (tx << 2) + j;
      dbc[(size_t)m * 64 + n] = acc[i][j] + bxp[n];
    }
}

// ---------------- dt GEMM + softplus: delta = sp(dt @ W_dt^T + b_dt) --------
__global__ __launch_bounds__(256) void gemm_dt_k(const float* __restrict__ dbc,
                                                 const float* __restrict__ Wdt,
                                                 const float* __restrict__ bdt,
                                                 float* __restrict__ delta) {
  float acc[4][4];
  int m0 = blockIdx.y * 64, n0 = blockIdx.x * 64;
  gemm64(dbc, 64, Wdt, DTR, DTR, m0, n0, acc);
  int tx = threadIdx.x & 15, ty = threadIdx.x >> 4;
  #pragma unroll
  for (int i = 0; i < 4; i++)
    #pragma unroll
    for (int j = 0; j < 4; j++) {
      int m = m0 + (ty << 2) + i, n = n0 + (tx << 2) + j;
      float xv = acc[i][j] + bdt[n];
      delta[(size_t)m * CE_ + n] = (xv > 20.f) ? xv : log1pf(__expf(xv));
    }
}

// ---------------- scan phase1: per-chunk partial state + delta-sum ----------
// one thread per channel; h[16] in registers; B_t tile staged in LDS
__global__ __launch_bounds__(256) void scan1_k(const float* __restrict__ delta,
                                               const float* __restrict__ dbc,
                                               const float* __restrict__ vs,
                                               const float* __restrict__ A_log,
                                               float* __restrict__ S,
                                               float* __restrict__ Dsum) {
  __shared__ float bt_s[CHL * NS];
  int b = blockIdx.z, ch = blockIdx.y;
  int c = blockIdx.x * 256 + threadIdx.x;
  int mbase = b * L_ + ch * CHL;
  for (int i = threadIdx.x; i < CHL * NS; i += 256)
    bt_s[i] = dbc[(size_t)(mbase + (i >> 4)) * 64 + DTR + (i & 15)];
  __syncthreads();
  float Ac[NS], h[NS];
  #pragma unroll
  for (int n = 0; n < NS; n++) {
    Ac[n] = -__expf(A_log[c * NS + n]);
    h[n] = 0.f;
  }
  float dsum = 0.f;
  for (int t = 0; t < CHL; t++) {
    int m = mbase + t;
    float d  = delta[(size_t)m * CE_ + c];
    float vv = vs[(size_t)m * CE_ + c];
    float dv = d * vv;
    dsum += d;
    #pragma unroll
    for (int n = 0; n < NS; n++)
      h[n] = fmaf(h[n], __expf(d * Ac[n]), dv * bt_s[t * NS + n]);
  }
  size_t sidx = (size_t)(b * NCH + ch) * CE_ + c;
  #pragma unroll
  for (int n = 0; n < NS; n++) S[sidx * NS + n] = h[n];
  Dsum[sidx] = dsum;
}

// ---------------- scan phase2: compose chunk boundaries (in-place S→hstart) -
__global__ __launch_bounds__(256) void scan2_k(const float* __restrict__ A_log,
                                               float* __restrict__ S,
                                               const float* __restrict__ Dsum) {
  int idx = blockIdx.x * 256 + threadIdx.x;   // B*CE*NS = 32768 total
  int n = idx & 15, c = (idx >> 4) & (CE_ - 1), b = idx >> 13;
  float Ac = -__expf(A_log[c * NS + n]);
  float h = 0.f;
  for (int ch = 0; ch < NCH; ch++) {
    size_t sidx = (size_t)(b * NCH + ch) * CE_ + c;
    float sv = S[sidx * NS + n];
    float ds = Dsum[sidx];
    S[sidx * NS + n] = h;                 // now holds h_start for this chunk
    h = fmaf(h, __expf(Ac * ds), sv);
  }
}

// ---------------- scan phase3: replay with h_start, y, fused z --------------
// z = y*g + gate = u * (y*sigmoid(u) + v_silu*sigmoid(-u))
__global__ __launch_bounds__(256) void scan3_k(const float* __restrict__ delta,
                                               const float* __restrict__ dbc,
                                               const float* __restrict__ vs,
                                               const float* __restrict__ A_log,
                                               const float* __restrict__ Dv,
                                               const float* __restrict__ hstart,
                                               const float* __restrict__ u,
                                               float* __restrict__ z) {
  __shared__ float bc_s[CHL * 32];
  int b = blockIdx.z, ch = blockIdx.y;
  int c = blockIdx.x * 256 + threadIdx.x;
  int mbase = b * L_ + ch * CHL;
  for (int i = threadIdx.x; i < CHL * 32; i += 256)
    bc_s[i] = dbc[(size_t)(mbase + (i >> 5)) * 64 + DTR + (i & 31)];
  __syncthreads();
  size_t sidx = (size_t)(b * NCH + ch) * CE_ + c;
  float Ac[NS], h[NS];
  #pragma unroll
  for (int n = 0; n < NS; n++) {
    Ac[n] = -__expf(A_log[c * NS + n]);
    h[n] = hstart[sidx * NS + n];
  }
  float Dc = Dv[c];
  for (int t = 0; t < CHL; t++) {
    int m = mbase + t;
    float d  = delta[(size_t)m * CE_ + c];
    float vv = vs[(size_t)m * CE_ + c];
    float dv = d * vv;
    float y = 0.f;
    #pragma unroll
    for (int n = 0; n < NS; n++) {
      h[n] = fmaf(h[n], __expf(d * Ac[n]), dv * bc_s[t * 32 + n]);
      y = fmaf(h[n], bc_s[t * 32 + 16 + n], y);
    }
    y = fmaf(Dc, vv, y);
    float uu = u[(size_t)m * CE_ + c];
    float s  = 1.f / (1.f + __expf(-uu));
    z[(size_t)m * CE_ + c] = uu * (y * s + vv * (1.f - s));
  }
}

// ---------------- out-proj GEMM + NCHW transpose ----------------------------
__global__ __launch_bounds__(256) void gemm_proj_k(const float* __restrict__ z,
                                                   const float* __restrict__ w_proj,
                                                   const float* __restrict__ b_proj,
                                                   float* __restrict__ out) {
  float acc[4][4];
  int m0 = blockIdx.y * 64, n0 = blockIdx.x * 64;
  gemm64(z, CE_, w_proj, CE_, CE_, m0, n0, acc);
  int tx = threadIdx.x & 15, ty = threadIdx.x >> 4;
  #pragma unroll
  for (int i = 0; i < 4; i++)
    #pragma unroll
    for (int j = 0; j < 4; j++) {
      int m = m0 + (ty << 2) + i, n = n0 + (tx << 2) + j;
      int b = m / L_, p = m - b * L_;
      out[((size_t)(b * C_ + n)) * L_ + p] = acc[i][j] + b_proj[n];
    }
}

extern "C" void kernel_launch(void* const* d_in, const int* in_sizes, int n_in,
                              void* d_out, int out_size, void* d_ws, size_t ws_size,
                              hipStream_t stream) {
  const float* x      = (const float*)d_in[0];
  const float* norm_w = (const float*)d_in[1];
  const float* norm_b = (const float*)d_in[2];
  const float* w_ex   = (const float*)d_in[3];
  const float* b_ex   = (const float*)d_in[4];
  const float* w_proj = (const float*)d_in[5];
  const float* b_proj = (const float*)d_in[6];
  const float* dw_k   = (const float*)d_in[7];
  const float* A_log  = (const float*)d_in[8];
  const float* Dv     = (const float*)d_in[9];
  const float* W_xp   = (const float*)d_in[10];
  const float* b_xp   = (const float*)d_in[11];
  const float* W_dt   = (const float*)d_in[12];
  const float* b_dt   = (const float*)d_in[13];
  float* out = (float*)d_out;

  float* ws = (float*)d_ws;
  float* u      = ws;                          // BL*CE
  float* vraw   = u      + (size_t)BL * CE_;   // BL*CE  (reused as z)
  float* vs     = vraw   + (size_t)BL * CE_;   // BL*CE
  float* delta  = vs     + (size_t)BL * CE_;   // BL*CE
  float* dbc    = delta  + (size_t)BL * CE_;   // BL*64
  float* S      = dbc    + (size_t)BL * 64;    // B*NCH*CE*NS (hstart in-place)
  float* Dsum   = S      + (size_t)B_ * NCH * CE_ * NS;  // B*NCH*CE
  float* xn = out;      // borrow output buffer for xn (exact size match)
  float* z  = vraw;

  ln_k<<<BL, 256, 0, stream>>>(x, norm_w, norm_b, xn);
  gemm_expand_k<<<dim3(16, 144), 256, 0, stream>>>(xn, w_ex, b_ex, u, vraw);
  dwconv_k<<<BL, 256, 0, stream>>>(vraw, dw_k, vs);
  gemm_xproj_k<<<dim3(1, 144), 256, 0, stream>>>(vs, W_xp, b_xp, dbc);
  gemm_dt_k<<<dim3(8, 144), 256, 0, stream>>>(dbc, W_dt, b_dt, delta);
  scan1_k<<<dim3(2, NCH, B_), 256, 0, stream>>>(delta, dbc, vs, A_log, S, Dsum);
  scan2_k<<<128, 256, 0, stream>>>(A_log, S, Dsum);
  scan3_k<<<dim3(2, NCH, B_), 256, 0, stream>>>(delta, dbc, vs, A_log, Dv, S, u, z);
  gemm_proj_k<<<dim3(4, 144), 256, 0, stream>>>(z, w_proj, b_proj, out);
}

// Round 3
// 274.043 us; speedup vs baseline: 2.0011x; 1.4287x over previous
//
#include <hip/hip_runtime.h>
#include <hip/hip_bf16.h>

#define B_   4
#define C_   256
#define HH   48
#define WW   48
#define L_   2304
#define BL   9216
#define CE_  512
#define NS   16
#define DTR  32
#define NCH  72
#define CHL  32

typedef __attribute__((ext_vector_type(8))) short s16x8;
typedef __attribute__((ext_vector_type(4))) float f32x4;

__device__ __forceinline__ ushort f2bf(float f) {
  union { float f; unsigned u; } v; v.f = f;
  unsigned r = v.u + 0x7fffu + ((v.u >> 16) & 1u);
  return (ushort)(r >> 16);
}
__device__ __forceinline__ float bf2f(ushort h) {
  union { unsigned u; float f; } v; v.u = ((unsigned)h) << 16;
  return v.f;
}

// ============== weight prep: casts + beff ====================================
__global__ __launch_bounds__(256) void prep_cast_k(const float* __restrict__ w_ex,
                                                   const float* __restrict__ w_proj,
                                                   const float* __restrict__ W_xp,
                                                   const float* __restrict__ b_xp,
                                                   const float* __restrict__ W_dt,
                                                   const float* __restrict__ b_dt,
                                                   ushort* __restrict__ w_ex_bf,
                                                   ushort* __restrict__ w_proj_bf,
                                                   ushort* __restrict__ wbc_bf,
                                                   float* __restrict__ beff) {
  int idx = blockIdx.x * 256 + threadIdx.x;
  if (idx < 262144) {
    w_ex_bf[idx] = f2bf(w_ex[idx]);
  } else if (idx < 393216) {
    int i = idx - 262144; w_proj_bf[i] = f2bf(w_proj[i]);
  } else if (idx < 409600) {
    int i = idx - 393216; wbc_bf[i] = f2bf(W_xp[32 * 512 + i]);
  } else if (idx < 410112) {
    int i = idx - 409600;
    float s = b_dt[i];
    #pragma unroll
    for (int r = 0; r < 32; r++) s = fmaf(W_dt[i * 32 + r], b_xp[r], s);
    beff[i] = s;
  }
}

// Weff[i][j] = sum_r W_dt[i][r] * W_xp[r][j]   (512x512, bf16 out)
__global__ __launch_bounds__(256) void weff_k(const float* __restrict__ W_dt,
                                              const float* __restrict__ W_xp,
                                              ushort* __restrict__ weff_bf) {
  int j = blockIdx.x * 64 + (threadIdx.x & 63);
  int i = blockIdx.y * 4 + (threadIdx.x >> 6);
  float s = 0.f;
  #pragma unroll
  for (int r = 0; r < 32; r++) s = fmaf(W_dt[i * 32 + r], W_xp[r * 512 + j], s);
  weff_bf[i * 512 + j] = f2bf(s);
}

// ============== LayerNorm: 16-pixel LDS tile, coalesced, bf16 out ===========
__global__ __launch_bounds__(256) void ln_k(const float* __restrict__ x,
                                            const float* __restrict__ w,
                                            const float* __restrict__ bia,
                                            ushort* __restrict__ xn_bf) {
  __shared__ float xt[C_][17];
  __shared__ float ps[16][17], ps2[16][17];
  __shared__ float mu_s[16], r_s[16];
  int blk = blockIdx.x;
  int b = blk / 144, p0 = (blk - b * 144) * 16;
  int t = threadIdx.x;
  // load 256x16 fp32 tile, coalesced over pixels
  #pragma unroll
  for (int it = 0; it < 16; it++) {
    int i = it * 256 + t;
    int c = i >> 4, pj = i & 15;
    xt[c][pj] = x[((size_t)(b * C_ + c)) * L_ + p0 + pj];
  }
  __syncthreads();
  // partial sums: 16 c-chunks x 16 pixels
  {
    int ci = t >> 4, pj = t & 15;
    float s = 0.f, s2 = 0.f;
    #pragma unroll
    for (int k = 0; k < 16; k++) {
      float v = xt[ci * 16 + k][pj];
      s += v; s2 += v * v;
    }
    ps[ci][pj] = s; ps2[ci][pj] = s2;
  }
  __syncthreads();
  if (t < 16) {
    float s = 0.f, s2 = 0.f;
    #pragma unroll
    for (int ci = 0; ci < 16; ci++) { s += ps[ci][t]; s2 += ps2[ci][t]; }
    float mu = s * (1.f / C_);
    float var = s2 * (1.f / C_) - mu * mu;
    mu_s[t] = mu; r_s[t] = rsqrtf(var + 1e-6f);
  }
  __syncthreads();
  float wr = w[t], br = bia[t];
  #pragma unroll
  for (int pj = 0; pj < 16; pj++) {
    float val = (xt[t][pj] - mu_s[pj]) * r_s[pj] * wr + br;
    xn_bf[((size_t)(b * L_ + p0 + pj)) * C_ + t] = f2bf(val);
  }
}

// ============== bf16 MFMA GEMM core:  C[TMxTN] = A(MxK) @ B(NxK)^T ==========
// LDS layout [BK/8=4][rows][8] -> conflict-free ds_read_b128; global_load_lds.
template<int TM, int TN, int WM, int WN, int FM, int FN, int K>
__device__ __forceinline__ void mfma_gemm(const ushort* __restrict__ A,
                                          const ushort* __restrict__ Bm,
                                          int m0, int n0,
                                          ushort* Als, ushort* Bls,
                                          f32x4 acc[FM][FN]) {
  const int t = threadIdx.x;
  const int lane = t & 63;
  const int wid = t >> 6;
  const int wm = wid / WN, wn = wid % WN;
  #pragma unroll
  for (int i = 0; i < FM; i++)
    #pragma unroll
    for (int j = 0; j < FN; j++) acc[i][j] = (f32x4){0.f, 0.f, 0.f, 0.f};

  for (int kt = 0; kt < K; kt += 32) {
    #pragma unroll
    for (int ch = t; ch < TM * 4; ch += 256) {
      int k8 = ch / TM, row = ch % TM;
      const ushort* g = A + (size_t)(m0 + row) * K + kt + k8 * 8;
      ushort* l = Als + (k8 * TM + row) * 8;
      __builtin_amdgcn_global_load_lds((const __attribute__((address_space(1))) void*)g,
                                       (__attribute__((address_space(3))) void*)l, 16, 0, 0);
    }
    #pragma unroll
    for (int ch = t; ch < TN * 4; ch += 256) {
      int k8 = ch / TN, row = ch % TN;
      const ushort* g = Bm + (size_t)(n0 + row) * K + kt + k8 * 8;
      ushort* l = Bls + (k8 * TN + row) * 8;
      __builtin_amdgcn_global_load_lds((const __attribute__((address_space(1))) void*)g,
                                       (__attribute__((address_space(3))) void*)l, 16, 0, 0);
    }
    __syncthreads();
    int k8 = lane >> 4, r = lane & 15;
    s16x8 a[FM], b[FN];
    #pragma unroll
    for (int i = 0; i < FM; i++)
      a[i] = *(const s16x8*)(Als + (k8 * TM + wm * FM * 16 + i * 16 + r) * 8);
    #pragma unroll
    for (int j = 0; j < FN; j++)
      b[j] = *(const s16x8*)(Bls + (k8 * TN + wn * FN * 16 + j * 16 + r) * 8);
    #pragma unroll
    for (int i = 0; i < FM; i++)
      #pragma unroll
      for (int j = 0; j < FN; j++)
        acc[i][j] = __builtin_amdgcn_mfma_f32_16x16x32_bf16(a[i], b[j], acc[i][j], 0, 0, 0);
    __syncthreads();
  }
}

// ---- expand: xn_bf[9216x256] @ w_ex_bf[1024x256]^T -> u_bf | vraw_bf -------
__global__ __launch_bounds__(256) void gemm_expand_k(const ushort* __restrict__ xn,
                                                     const ushort* __restrict__ wex,
                                                     const float* __restrict__ b_ex,
                                                     ushort* __restrict__ u_bf,
                                                     ushort* __restrict__ v_bf) {
  __shared__ alignas(16) ushort Als[4 * 128 * 8];
  __shared__ alignas(16) ushort Bls[4 * 128 * 8];
  f32x4 acc[4][4];
  int m0 = blockIdx.y * 128, n0 = blockIdx.x * 128;
  mfma_gemm<128, 128, 2, 2, 4, 4, 256>(xn, wex, m0, n0, Als, Bls, acc);
  int lane = threadIdx.x & 63, wid = threadIdx.x >> 6;
  int wm = wid >> 1, wn = wid & 1;
  int q4 = (lane >> 4) * 4, cix = lane & 15;
  #pragma unroll
  for (int j = 0; j < 4; j++) {
    int nc = n0 + wn * 64 + j * 16 + cix;
    float bias = b_ex[nc];
    ushort* dst = (n0 < 512) ? (u_bf + nc) : (v_bf + nc - 512);
    #pragma unroll
    for (int i = 0; i < 4; i++) {
      int mr = m0 + wm * 64 + i * 16 + q4;
      #pragma unroll
      for (int q = 0; q < 4; q++)
        dst[(size_t)(mr + q) * CE_] = f2bf(acc[i][j][q] + bias);
    }
  }
}

// ---- delta: vs_bf @ weff_bf^T + beff -> softplus -> delta fp32 -------------
__global__ __launch_bounds__(256) void gemm_delta_k(const ushort* __restrict__ vs,
                                                    const ushort* __restrict__ weff,
                                                    const float* __restrict__ beff,
                                                    float* __restrict__ delta) {
  __shared__ alignas(16) ushort Als[4 * 128 * 8];
  __shared__ alignas(16) ushort Bls[4 * 128 * 8];
  f32x4 acc[4][4];
  int m0 = blockIdx.y * 128, n0 = blockIdx.x * 128;
  mfma_gemm<128, 128, 2, 2, 4, 4, 512>(vs, weff, m0, n0, Als, Bls, acc);
  int lane = threadIdx.x & 63, wid = threadIdx.x >> 6;
  int wm = wid >> 1, wn = wid & 1;
  int q4 = (lane >> 4) * 4, cix = lane & 15;
  #pragma unroll
  for (int j = 0; j < 4; j++) {
    int nc = n0 + wn * 64 + j * 16 + cix;
    float bias = beff[nc];
    #pragma unroll
    for (int i = 0; i < 4; i++) {
      int mr = m0 + wm * 64 + i * 16 + q4;
      #pragma unroll
      for (int q = 0; q < 4; q++) {
        float xv = acc[i][j][q] + bias;
        delta[(size_t)(mr + q) * CE_ + nc] = (xv > 20.f) ? xv : log1pf(__expf(xv));
      }
    }
  }
}

// ---- B/C: vs_bf @ wbc_bf[32x512]^T + b_xp[32..63] -> bc fp32 [m][32] -------
__global__ __launch_bounds__(256) void gemm_bc_k(const ushort* __restrict__ vs,
                                                 const ushort* __restrict__ wbc,
                                                 const float* __restrict__ b_xp,
                                                 float* __restrict__ bc) {
  __shared__ alignas(16) ushort Als[4 * 64 * 8];
  __shared__ alignas(16) ushort Bls[4 * 32 * 8];
  f32x4 acc[1][2];
  int m0 = blockIdx.y * 64, n0 = 0;
  mfma_gemm<64, 32, 4, 1, 1, 2, 512>(vs, wbc, m0, n0, Als, Bls, acc);
  int lane = threadIdx.x & 63, wid = threadIdx.x >> 6;
  int q4 = (lane >> 4) * 4, cix = lane & 15;
  #pragma unroll
  for (int j = 0; j < 2; j++) {
    int nc = j * 16 + cix;
    float bias = b_xp[32 + nc];
    int mr = m0 + wid * 16 + q4;
    #pragma unroll
    for (int q = 0; q < 4; q++)
      bc[(size_t)(mr + q) * 32 + nc] = acc[0][j][q] + bias;
  }
}

// ---- proj: z_bf @ w_proj_bf[256x512]^T + b_proj -> out NCHW fp32 -----------
__global__ __launch_bounds__(256) void gemm_proj_k(const ushort* __restrict__ z,
                                                   const ushort* __restrict__ wpr,
                                                   const float* __restrict__ b_proj,
                                                   float* __restrict__ out) {
  __shared__ alignas(16) ushort Als[4 * 64 * 8];
  __shared__ alignas(16) ushort Bls[4 * 128 * 8];
  f32x4 acc[2][4];
  int m0 = blockIdx.y * 64, n0 = blockIdx.x * 128;
  mfma_gemm<64, 128, 2, 2, 2, 4, 512>(z, wpr, m0, n0, Als, Bls, acc);
  int lane = threadIdx.x & 63, wid = threadIdx.x >> 6;
  int wm = wid >> 1, wn = wid & 1;
  int q4 = (lane >> 4) * 4, cix = lane & 15;
  #pragma unroll
  for (int j = 0; j < 4; j++) {
    int nc = n0 + wn * 64 + j * 16 + cix;
    float bias = b_proj[nc];
    #pragma unroll
    for (int i = 0; i < 2; i++) {
      int pix = m0 + wm * 32 + i * 16 + q4;
      int b = pix / L_, p = pix - b * L_;
      float4 vv = make_float4(acc[i][j][0] + bias, acc[i][j][1] + bias,
                              acc[i][j][2] + bias, acc[i][j][3] + bias);
      *(float4*)&out[((size_t)(b * C_ + nc)) * L_ + p] = vv;
    }
  }
}

// ============== depthwise 3x3 conv (SAME) + SiLU, bf16 in/out ===============
__global__ __launch_bounds__(256) void dwconv_k(const ushort* __restrict__ vraw,
                                                const float* __restrict__ kw,
                                                ushort* __restrict__ vs) {
  int p = blockIdx.x;
  int b = p / L_, q = p - b * L_;
  int y = q / WW, x = q - y * WW;
  int c2 = threadIdx.x;           // channels 2*c2, 2*c2+1
  float a0 = 0.f, a1 = 0.f;
  #pragma unroll
  for (int ky = 0; ky < 3; ky++) {
    int yy = y + ky - 1;
    if (yy < 0 || yy >= HH) continue;
    #pragma unroll
    for (int kx = 0; kx < 3; kx++) {
      int xx = x + kx - 1;
      if (xx < 0 || xx >= WW) continue;
      unsigned pv = *(const unsigned*)(vraw + ((size_t)(b * L_ + yy * WW + xx)) * CE_ + 2 * c2);
      float2 kk = *(const float2*)(kw + (ky * 3 + kx) * CE_ + 2 * c2);
      a0 = fmaf(bf2f((ushort)(pv & 0xffff)), kk.x, a0);
      a1 = fmaf(bf2f((ushort)(pv >> 16)), kk.y, a1);
    }
  }
  float s0 = a0 / (1.f + __expf(-a0));
  float s1 = a1 / (1.f + __expf(-a1));
  unsigned outp = (unsigned)f2bf(s0) | ((unsigned)f2bf(s1) << 16);
  *(unsigned*)(vs + (size_t)p * CE_ + 2 * c2) = outp;
}

// ============== scan phase1 =================================================
__global__ __launch_bounds__(256) void scan1_k(const float* __restrict__ delta,
                                               const float* __restrict__ bc,
                                               const ushort* __restrict__ vs,
                                               const float* __restrict__ A_log,
                                               float* __restrict__ S,
                                               float* __restrict__ Dsum) {
  __shared__ float bt_s[CHL * NS];
  int b = blockIdx.z, ch = blockIdx.y;
  int c = blockIdx.x * 256 + threadIdx.x;
  int mbase = b * L_ + ch * CHL;
  for (int i = threadIdx.x; i < CHL * NS; i += 256)
    bt_s[i] = bc[(size_t)(mbase + (i >> 4)) * 32 + (i & 15)];
  __syncthreads();
  float Ac[NS], h[NS];
  #pragma unroll
  for (int n = 0; n < NS; n++) {
    Ac[n] = -__expf(A_log[c * NS + n]);
    h[n] = 0.f;
  }
  float dsum = 0.f;
  for (int t = 0; t < CHL; t++) {
    int m = mbase + t;
    float d  = delta[(size_t)m * CE_ + c];
    float vv = bf2f(vs[(size_t)m * CE_ + c]);
    float dv = d * vv;
    dsum += d;
    #pragma unroll
    for (int n = 0; n < NS; n++)
      h[n] = fmaf(h[n], __expf(d * Ac[n]), dv * bt_s[t * NS + n]);
  }
  size_t sidx = (size_t)(b * NCH + ch) * CE_ + c;
  #pragma unroll
  for (int n = 0; n < NS; n++) S[sidx * NS + n] = h[n];
  Dsum[sidx] = dsum;
}

// ============== scan phase2: compose boundaries in-place ====================
__global__ __launch_bounds__(256) void scan2_k(const float* __restrict__ A_log,
                                               float* __restrict__ S,
                                               const float* __restrict__ Dsum) {
  int idx = blockIdx.x * 256 + threadIdx.x;   // B*CE*NS = 32768
  int n = idx & 15, c = (idx >> 4) & (CE_ - 1), b = idx >> 13;
  float Ac = -__expf(A_log[c * NS + n]);
  float h = 0.f;
  for (int ch = 0; ch < NCH; ch++) {
    size_t sidx = (size_t)(b * NCH + ch) * CE_ + c;
    float sv = S[sidx * NS + n];
    float ds = Dsum[sidx];
    S[sidx * NS + n] = h;
    h = fmaf(h, __expf(Ac * ds), sv);
  }
}

// ============== scan phase3: replay + y + fused z (bf16 out) ================
__global__ __launch_bounds__(256) void scan3_k(const float* __restrict__ delta,
                                               const float* __restrict__ bc,
                                               const ushort* __restrict__ vs,
                                               const float* __restrict__ A_log,
                                               const float* __restrict__ Dv,
                                               const float* __restrict__ hstart,
                                               const ushort* __restrict__ u,
                                               ushort* __restrict__ z) {
  __shared__ float bc_s[CHL * 32];
  int b = blockIdx.z, ch = blockIdx.y;
  int c = blockIdx.x * 256 + threadIdx.x;
  int mbase = b * L_ + ch * CHL;
  for (int i = threadIdx.x; i < CHL * 32; i += 256)
    bc_s[i] = bc[(size_t)(mbase + (i >> 5)) * 32 + (i & 31)];
  __syncthreads();
  size_t sidx = (size_t)(b * NCH + ch) * CE_ + c;
  float Ac[NS], h[NS];
  #pragma unroll
  for (int n = 0; n < NS; n++) {
    Ac[n] = -__expf(A_log[c * NS + n]);
    h[n] = hstart[sidx * NS + n];
  }
  float Dc = Dv[c];
  for (int t = 0; t < CHL; t++) {
    int m = mbase + t;
    float d  = delta[(size_t)m * CE_ + c];
    float vv = bf2f(vs[(size_t)m * CE_ + c]);
    float dv = d * vv;
    float y = 0.f;
    #pragma unroll
    for (int n = 0; n < NS; n++) {
      h[n] = fmaf(h[n], __expf(d * Ac[n]), dv * bc_s[t * 32 + n]);
      y = fmaf(h[n], bc_s[t * 32 + 16 + n], y);
    }
    y = fmaf(Dc, vv, y);
    float uu = bf2f(u[(size_t)m * CE_ + c]);
    float s  = 1.f / (1.f + __expf(-uu));
    z[(size_t)m * CE_ + c] = f2bf(uu * (y * s + vv * (1.f - s)));
  }
}

extern "C" void kernel_launch(void* const* d_in, const int* in_sizes, int n_in,
                              void* d_out, int out_size, void* d_ws, size_t ws_size,
                              hipStream_t stream) {
  const float* x      = (const float*)d_in[0];
  const float* norm_w = (const float*)d_in[1];
  const float* norm_b = (const float*)d_in[2];
  const float* w_ex   = (const float*)d_in[3];
  const float* b_ex   = (const float*)d_in[4];
  const float* w_proj = (const float*)d_in[5];
  const float* b_proj = (const float*)d_in[6];
  const float* dw_k   = (const float*)d_in[7];
  const float* A_log  = (const float*)d_in[8];
  const float* Dv     = (const float*)d_in[9];
  const float* W_xp   = (const float*)d_in[10];
  const float* b_xp   = (const float*)d_in[11];
  const float* W_dt   = (const float*)d_in[12];
  const float* b_dt   = (const float*)d_in[13];
  float* out = (float*)d_out;

  char* wsb = (char*)d_ws;
  size_t off = 0;
  auto alloc = [&](size_t bytes) { void* p = wsb + off; off += (bytes + 255) & ~(size_t)255; return p; };
  ushort* u_bf    = (ushort*)alloc((size_t)BL * CE_ * 2);
  ushort* vraw_bf = (ushort*)alloc((size_t)BL * CE_ * 2);   // reused as z_bf
  ushort* vs_bf   = (ushort*)alloc((size_t)BL * CE_ * 2);
  ushort* xn_bf   = (ushort*)alloc((size_t)BL * C_ * 2);
  float*  delta   = (float*)alloc((size_t)BL * CE_ * 4);
  float*  bc      = (float*)alloc((size_t)BL * 32 * 4);
  float*  S       = (float*)alloc((size_t)B_ * NCH * CE_ * NS * 4);
  float*  Dsum    = (float*)alloc((size_t)B_ * NCH * CE_ * 4);
  ushort* w_ex_bf = (ushort*)alloc((size_t)2 * CE_ * C_ * 2);
  ushort* w_pr_bf = (ushort*)alloc((size_t)C_ * CE_ * 2);
  ushort* wbc_bf  = (ushort*)alloc((size_t)32 * CE_ * 2);
  ushort* weff_bf = (ushort*)alloc((size_t)CE_ * CE_ * 2);
  float*  beff    = (float*)alloc((size_t)CE_ * 4);
  ushort* z_bf = vraw_bf;

  prep_cast_k<<<1602, 256, 0, stream>>>(w_ex, w_proj, W_xp, b_xp, W_dt, b_dt,
                                        w_ex_bf, w_pr_bf, wbc_bf, beff);
  weff_k<<<dim3(8, 128), 256, 0, stream>>>(W_dt, W_xp, weff_bf);
  ln_k<<<576, 256, 0, stream>>>(x, norm_w, norm_b, xn_bf);
  gemm_expand_k<<<dim3(8, 72), 256, 0, stream>>>(xn_bf, w_ex_bf, b_ex, u_bf, vraw_bf);
  dwconv_k<<<BL, 256, 0, stream>>>(vraw_bf, dw_k, vs_bf);
  gemm_delta_k<<<dim3(4, 72), 256, 0, stream>>>(vs_bf, weff_bf, beff, delta);
  gemm_bc_k<<<dim3(1, 144), 256, 0, stream>>>(vs_bf, wbc_bf, b_xp, bc);
  scan1_k<<<dim3(2, NCH, B_), 256, 0, stream>>>(delta, bc, vs_bf, A_log, S, Dsum);
  scan2_k<<<128, 256, 0, stream>>>(A_log, S, Dsum);
  scan3_k<<<dim3(2, NCH, B_), 256, 0, stream>>>(delta, bc, vs_bf, A_log, Dv, S, u_bf, z_bf);
  gemm_proj_k<<<dim3(2, 144), 256, 0, stream>>>(z_bf, w_pr_bf, b_proj, out);
}

// Round 4
// 243.228 us; speedup vs baseline: 2.2546x; 1.1267x over previous
//
#include <hip/hip_runtime.h>
#include <hip/hip_bf16.h>

#define B_   4
#define C_   256
#define HH   48
#define WW   48
#define L_   2304
#define BL   9216
#define CE_  512
#define NS   16
#define DTR  32
#define NCH  72
#define CHL  32

typedef __attribute__((ext_vector_type(8))) short s16x8;
typedef __attribute__((ext_vector_type(4))) float f32x4;

__device__ __forceinline__ ushort f2bf(float f) {
  union { float f; unsigned u; } v; v.f = f;
  unsigned r = v.u + 0x7fffu + ((v.u >> 16) & 1u);
  return (ushort)(r >> 16);
}
__device__ __forceinline__ float bf2f(ushort h) {
  union { unsigned u; float f; } v; v.u = ((unsigned)h) << 16;
  return v.f;
}

// ============== weight prep: casts + fused bias ==============================
__global__ __launch_bounds__(256) void prep_cast_k(const float* __restrict__ w_ex,
                                                   const float* __restrict__ w_proj,
                                                   const float* __restrict__ b_xp,
                                                   const float* __restrict__ W_dt,
                                                   const float* __restrict__ b_dt,
                                                   ushort* __restrict__ w_ex_bf,
                                                   ushort* __restrict__ w_proj_bf,
                                                   float* __restrict__ bcat) {
  int idx = blockIdx.x * 256 + threadIdx.x;
  if (idx < 262144) {
    w_ex_bf[idx] = f2bf(w_ex[idx]);
  } else if (idx < 393216) {
    int i = idx - 262144; w_proj_bf[i] = f2bf(w_proj[i]);
  } else if (idx < 393792) {
    int n = idx - 393216;               // 0..575
    float s;
    if (n < 512) {
      s = b_dt[n];
      #pragma unroll
      for (int r = 0; r < 32; r++) s = fmaf(W_dt[n * 32 + r], b_xp[r], s);
    } else if (n < 544) {
      s = b_xp[32 + (n - 512)];
    } else s = 0.f;
    bcat[n] = s;
  }
}

// wcat[576][512]: rows 0-511 = W_dt@W_xp[:32] ; 512-543 = W_xp rows 32-63 ; rest 0
__global__ __launch_bounds__(256) void wcat_k(const float* __restrict__ W_dt,
                                              const float* __restrict__ W_xp,
                                              ushort* __restrict__ wcat_bf) {
  int idx = blockIdx.x * 256 + threadIdx.x;   // 576*512 = 294912
  int i = idx >> 9, j = idx & 511;
  float s = 0.f;
  if (i < 512) {
    #pragma unroll
    for (int r = 0; r < 32; r++) s = fmaf(W_dt[i * 32 + r], W_xp[r * 512 + j], s);
  } else if (i < 544) {
    s = W_xp[(i - 480) * 512 + j];
  }
  wcat_bf[idx] = f2bf(s);
}

// ============== LayerNorm: 16-pixel LDS tile, coalesced, bf16 out ===========
__global__ __launch_bounds__(256) void ln_k(const float* __restrict__ x,
                                            const float* __restrict__ w,
                                            const float* __restrict__ bia,
                                            ushort* __restrict__ xn_bf) {
  __shared__ float xt[C_][17];
  __shared__ float ps[16][17], ps2[16][17];
  __shared__ float mu_s[16], r_s[16];
  int blk = blockIdx.x;
  int b = blk / 144, p0 = (blk - b * 144) * 16;
  int t = threadIdx.x;
  #pragma unroll
  for (int it = 0; it < 16; it++) {
    int i = it * 256 + t;
    int c = i >> 4, pj = i & 15;
    xt[c][pj] = x[((size_t)(b * C_ + c)) * L_ + p0 + pj];
  }
  __syncthreads();
  {
    int ci = t >> 4, pj = t & 15;
    float s = 0.f, s2 = 0.f;
    #pragma unroll
    for (int k = 0; k < 16; k++) {
      float v = xt[ci * 16 + k][pj];
      s += v; s2 += v * v;
    }
    ps[ci][pj] = s; ps2[ci][pj] = s2;
  }
  __syncthreads();
  if (t < 16) {
    float s = 0.f, s2 = 0.f;
    #pragma unroll
    for (int ci = 0; ci < 16; ci++) { s += ps[ci][t]; s2 += ps2[ci][t]; }
    float mu = s * (1.f / C_);
    float var = s2 * (1.f / C_) - mu * mu;
    mu_s[t] = mu; r_s[t] = rsqrtf(var + 1e-6f);
  }
  __syncthreads();
  float wr = w[t], br = bia[t];
  #pragma unroll
  for (int pj = 0; pj < 16; pj++) {
    float val = (xt[t][pj] - mu_s[pj]) * r_s[pj] * wr + br;
    xn_bf[((size_t)(b * L_ + p0 + pj)) * C_ + t] = f2bf(val);
  }
}

// ============== bf16 MFMA GEMM core:  C[TMxTN] = A(MxK) @ B(NxK)^T ==========
template<int TM, int TN, int WN, int FM, int FN, int K>
__device__ __forceinline__ void mfma_gemm(const ushort* __restrict__ A,
                                          const ushort* __restrict__ Bm,
                                          int m0, int n0,
                                          ushort* Als, ushort* Bls,
                                          f32x4 acc[FM][FN]) {
  const int t = threadIdx.x;
  const int lane = t & 63;
  const int wid = t >> 6;
  const int wm = wid / WN, wn = wid % WN;
  #pragma unroll
  for (int i = 0; i < FM; i++)
    #pragma unroll
    for (int j = 0; j < FN; j++) acc[i][j] = (f32x4){0.f, 0.f, 0.f, 0.f};

  for (int kt = 0; kt < K; kt += 32) {
    #pragma unroll
    for (int ch = t; ch < TM * 4; ch += 256) {
      int k8 = ch / TM, row = ch % TM;
      const ushort* g = A + (size_t)(m0 + row) * K + kt + k8 * 8;
      ushort* l = Als + (k8 * TM + row) * 8;
      __builtin_amdgcn_global_load_lds((const __attribute__((address_space(1))) void*)g,
                                       (__attribute__((address_space(3))) void*)l, 16, 0, 0);
    }
    #pragma unroll
    for (int ch = t; ch < TN * 4; ch += 256) {
      int k8 = ch / TN, row = ch % TN;
      const ushort* g = Bm + (size_t)(n0 + row) * K + kt + k8 * 8;
      ushort* l = Bls + (k8 * TN + row) * 8;
      __builtin_amdgcn_global_load_lds((const __attribute__((address_space(1))) void*)g,
                                       (__attribute__((address_space(3))) void*)l, 16, 0, 0);
    }
    __syncthreads();
    int k8 = lane >> 4, r = lane & 15;
    s16x8 a[FM], b[FN];
    #pragma unroll
    for (int i = 0; i < FM; i++)
      a[i] = *(const s16x8*)(Als + (k8 * TM + wm * FM * 16 + i * 16 + r) * 8);
    #pragma unroll
    for (int j = 0; j < FN; j++)
      b[j] = *(const s16x8*)(Bls + (k8 * TN + wn * FN * 16 + j * 16 + r) * 8);
    #pragma unroll
    for (int i = 0; i < FM; i++)
      #pragma unroll
      for (int j = 0; j < FN; j++)
        acc[i][j] = __builtin_amdgcn_mfma_f32_16x16x32_bf16(a[i], b[j], acc[i][j], 0, 0, 0);
    __syncthreads();
  }
}

// ---- expand: xn_bf[9216x256] @ w_ex_bf[1024x256]^T -> u_bf | vraw_bf -------
__global__ __launch_bounds__(256) void gemm_expand_k(const ushort* __restrict__ xn,
                                                     const ushort* __restrict__ wex,
                                                     const float* __restrict__ b_ex,
                                                     ushort* __restrict__ u_bf,
                                                     ushort* __restrict__ v_bf) {
  __shared__ alignas(16) ushort Als[4 * 128 * 8];
  __shared__ alignas(16) ushort Bls[4 * 64 * 8];
  f32x4 acc[4][2];
  int m0 = blockIdx.y * 128, n0 = blockIdx.x * 64;
  mfma_gemm<128, 64, 2, 4, 2, 256>(xn, wex, m0, n0, Als, Bls, acc);
  int lane = threadIdx.x & 63, wid = threadIdx.x >> 6;
  int wm = wid >> 1, wn = wid & 1;
  int q4 = (lane >> 4) * 4, cix = lane & 15;
  ushort* base = (n0 < 512) ? u_bf : v_bf;
  int nbase = (n0 < 512) ? n0 : n0 - 512;
  #pragma unroll
  for (int j = 0; j < 2; j++) {
    int nc = nbase + wn * 32 + j * 16 + cix;
    float bias = b_ex[(n0 < 512 ? 0 : 512) + nc];
    #pragma unroll
    for (int i = 0; i < 4; i++) {
      int mr = m0 + wm * 64 + i * 16 + q4;
      #pragma unroll
      for (int q = 0; q < 4; q++)
        base[(size_t)(mr + q) * CE_ + nc] = f2bf(acc[i][j][q] + bias);
    }
  }
}

// ---- fused delta+bc: vs @ wcat[576x512]^T + bcat ---------------------------
__global__ __launch_bounds__(256) void gemm_dbc_k(const ushort* __restrict__ vs,
                                                  const ushort* __restrict__ wcat,
                                                  const float* __restrict__ bcat,
                                                  float* __restrict__ delta,
                                                  float* __restrict__ bc) {
  __shared__ alignas(16) ushort Als[4 * 128 * 8];
  __shared__ alignas(16) ushort Bls[4 * 64 * 8];
  f32x4 acc[4][2];
  int m0 = blockIdx.y * 128, n0 = blockIdx.x * 64;
  mfma_gemm<128, 64, 2, 4, 2, 512>(vs, wcat, m0, n0, Als, Bls, acc);
  int lane = threadIdx.x & 63, wid = threadIdx.x >> 6;
  int wm = wid >> 1, wn = wid & 1;
  int q4 = (lane >> 4) * 4, cix = lane & 15;
  #pragma unroll
  for (int j = 0; j < 2; j++) {
    int nc = n0 + wn * 32 + j * 16 + cix;
    if (nc >= 544) continue;
    float bias = bcat[nc];
    #pragma unroll
    for (int i = 0; i < 4; i++) {
      int mr = m0 + wm * 64 + i * 16 + q4;
      #pragma unroll
      for (int q = 0; q < 4; q++) {
        float xv = acc[i][j][q] + bias;
        if (nc < 512)
          delta[(size_t)(mr + q) * CE_ + nc] =
              fmaxf(xv, 0.f) + __logf(1.f + __expf(-fabsf(xv)));
        else
          bc[(size_t)(mr + q) * 32 + (nc - 512)] = xv;
      }
    }
  }
}

// ---- proj: z_bf @ w_proj_bf[256x512]^T + b_proj -> out NCHW fp32 -----------
__global__ __launch_bounds__(256) void gemm_proj_k(const ushort* __restrict__ z,
                                                   const ushort* __restrict__ wpr,
                                                   const float* __restrict__ b_proj,
                                                   float* __restrict__ out) {
  __shared__ alignas(16) ushort Als[4 * 64 * 8];
  __shared__ alignas(16) ushort Bls[4 * 64 * 8];
  f32x4 acc[2][2];
  int m0 = blockIdx.y * 64, n0 = blockIdx.x * 64;
  mfma_gemm<64, 64, 2, 2, 2, 512>(z, wpr, m0, n0, Als, Bls, acc);
  int lane = threadIdx.x & 63, wid = threadIdx.x >> 6;
  int wm = wid >> 1, wn = wid & 1;
  int q4 = (lane >> 4) * 4, cix = lane & 15;
  #pragma unroll
  for (int j = 0; j < 2; j++) {
    int nc = n0 + wn * 32 + j * 16 + cix;
    float bias = b_proj[nc];
    #pragma unroll
    for (int i = 0; i < 2; i++) {
      int pix = m0 + wm * 32 + i * 16 + q4;
      int b = pix / L_, p = pix - b * L_;
      float4 vv = make_float4(acc[i][j][0] + bias, acc[i][j][1] + bias,
                              acc[i][j][2] + bias, acc[i][j][3] + bias);
      *(float4*)&out[((size_t)(b * C_ + nc)) * L_ + p] = vv;
    }
  }
}

// ============== depthwise 3x3 conv (SAME) + SiLU, bf16 in/out ===============
__global__ __launch_bounds__(256) void dwconv_k(const ushort* __restrict__ vraw,
                                                const float* __restrict__ kw,
                                                ushort* __restrict__ vs) {
  int p = blockIdx.x * 2 + (threadIdx.x >> 7);
  int b = p / L_, q = p - b * L_;
  int y = q / WW, x = q - y * WW;
  int c4 = (threadIdx.x & 127) * 4;
  float a0 = 0.f, a1 = 0.f, a2 = 0.f, a3 = 0.f;
  #pragma unroll
  for (int ky = 0; ky < 3; ky++) {
    int yy = y + ky - 1;
    if (yy < 0 || yy >= HH) continue;
    #pragma unroll
    for (int kx = 0; kx < 3; kx++) {
      int xx = x + kx - 1;
      if (xx < 0 || xx >= WW) continue;
      uint2 pv = *(const uint2*)(vraw + ((size_t)(b * L_ + yy * WW + xx)) * CE_ + c4);
      float4 kk = *(const float4*)(kw + (ky * 3 + kx) * CE_ + c4);
      a0 = fmaf(bf2f((ushort)(pv.x & 0xffff)), kk.x, a0);
      a1 = fmaf(bf2f((ushort)(pv.x >> 16)),    kk.y, a1);
      a2 = fmaf(bf2f((ushort)(pv.y & 0xffff)), kk.z, a2);
      a3 = fmaf(bf2f((ushort)(pv.y >> 16)),    kk.w, a3);
    }
  }
  float s0 = a0 / (1.f + __expf(-a0));
  float s1 = a1 / (1.f + __expf(-a1));
  float s2 = a2 / (1.f + __expf(-a2));
  float s3 = a3 / (1.f + __expf(-a3));
  uint2 outp;
  outp.x = (unsigned)f2bf(s0) | ((unsigned)f2bf(s1) << 16);
  outp.y = (unsigned)f2bf(s2) | ((unsigned)f2bf(s3) << 16);
  *(uint2*)(vs + (size_t)p * CE_ + c4) = outp;
}

// ============== scan phase1 =================================================
__global__ __launch_bounds__(256) void scan1_k(const float* __restrict__ delta,
                                               const float* __restrict__ bc,
                                               const ushort* __restrict__ vs,
                                               const float* __restrict__ A_log,
                                               float* __restrict__ S,
                                               float* __restrict__ Dsum) {
  __shared__ float bt_s[CHL * NS];
  int b = blockIdx.z, ch = blockIdx.y;
  int c = blockIdx.x * 256 + threadIdx.x;
  int mbase = b * L_ + ch * CHL;
  for (int i = threadIdx.x; i < CHL * NS; i += 256)
    bt_s[i] = bc[(size_t)(mbase + (i >> 4)) * 32 + (i & 15)];
  __syncthreads();
  float Ac[NS], h[NS];
  #pragma unroll
  for (int n = 0; n < NS; n++) {
    Ac[n] = -__expf(A_log[c * NS + n]);
    h[n] = 0.f;
  }
  float dsum = 0.f;
  for (int t = 0; t < CHL; t++) {
    int m = mbase + t;
    float d  = delta[(size_t)m * CE_ + c];
    float vv = bf2f(vs[(size_t)m * CE_ + c]);
    float dv = d * vv;
    dsum += d;
    #pragma unroll
    for (int n = 0; n < NS; n++)
      h[n] = fmaf(h[n], __expf(d * Ac[n]), dv * bt_s[t * NS + n]);
  }
  size_t sidx = (size_t)(b * NCH + ch) * CE_ + c;
  #pragma unroll
  for (int n = 0; n < NS; n++) S[sidx * NS + n] = h[n];
  Dsum[sidx] = dsum;
}

// ============== scan phase2: compose boundaries in-place ====================
__global__ __launch_bounds__(256) void scan2_k(const float* __restrict__ A_log,
                                               float* __restrict__ S,
                                               const float* __restrict__ Dsum) {
  int idx = blockIdx.x * 256 + threadIdx.x;   // B*CE*NS = 32768
  int n = idx & 15, c = (idx >> 4) & (CE_ - 1), b = idx >> 13;
  float Ac = -__expf(A_log[c * NS + n]);
  float h = 0.f;
  for (int ch = 0; ch < NCH; ch++) {
    size_t sidx = (size_t)(b * NCH + ch) * CE_ + c;
    float sv = S[sidx * NS + n];
    float ds = Dsum[sidx];
    S[sidx * NS + n] = h;
    h = fmaf(h, __expf(Ac * ds), sv);
  }
}

// ============== scan phase3: replay + y + fused z (bf16 out) ================
__global__ __launch_bounds__(256) void scan3_k(const float* __restrict__ delta,
                                               const float* __restrict__ bc,
                                               const ushort* __restrict__ vs,
                                               const float* __restrict__ A_log,
                                               const float* __restrict__ Dv,
                                               const float* __restrict__ hstart,
                                               const ushort* __restrict__ u,
                                               ushort* __restrict__ z) {
  __shared__ float bc_s[CHL * 32];
  int b = blockIdx.z, ch = blockIdx.y;
  int c = blockIdx.x * 256 + threadIdx.x;
  int mbase = b * L_ + ch * CHL;
  for (int i = threadIdx.x; i < CHL * 32; i += 256)
    bc_s[i] = bc[(size_t)(mbase + (i >> 5)) * 32 + (i & 31)];
  __syncthreads();
  size_t sidx = (size_t)(b * NCH + ch) * CE_ + c;
  float Ac[NS], h[NS];
  #pragma unroll
  for (int n = 0; n < NS; n++) {
    Ac[n] = -__expf(A_log[c * NS + n]);
    h[n] = hstart[sidx * NS + n];
  }
  float Dc = Dv[c];
  for (int t = 0; t < CHL; t++) {
    int m = mbase + t;
    float d  = delta[(size_t)m * CE_ + c];
    float vv = bf2f(vs[(size_t)m * CE_ + c]);
    float dv = d * vv;
    float y = 0.f;
    #pragma unroll
    for (int n = 0; n < NS; n++) {
      h[n] = fmaf(h[n], __expf(d * Ac[n]), dv * bc_s[t * 32 + n]);
      y = fmaf(h[n], bc_s[t * 32 + 16 + n], y);
    }
    y = fmaf(Dc, vv, y);
    float uu = bf2f(u[(size_t)m * CE_ + c]);
    float s  = 1.f / (1.f + __expf(-uu));
    z[(size_t)m * CE_ + c] = f2bf(uu * (y * s + vv * (1.f - s)));
  }
}

extern "C" void kernel_launch(void* const* d_in, const int* in_sizes, int n_in,
                              void* d_out, int out_size, void* d_ws, size_t ws_size,
                              hipStream_t stream) {
  const float* x      = (const float*)d_in[0];
  const float* norm_w = (const float*)d_in[1];
  const float* norm_b = (const float*)d_in[2];
  const float* w_ex   = (const float*)d_in[3];
  const float* b_ex   = (const float*)d_in[4];
  const float* w_proj = (const float*)d_in[5];
  const float* b_proj = (const float*)d_in[6];
  const float* dw_k   = (const float*)d_in[7];
  const float* A_log  = (const float*)d_in[8];
  const float* Dv     = (const float*)d_in[9];
  const float* W_xp   = (const float*)d_in[10];
  const float* b_xp   = (const float*)d_in[11];
  const float* W_dt   = (const float*)d_in[12];
  const float* b_dt   = (const float*)d_in[13];
  float* out = (float*)d_out;

  char* wsb = (char*)d_ws;
  size_t off = 0;
  auto alloc = [&](size_t bytes) { void* p = wsb + off; off += (bytes + 255) & ~(size_t)255; return p; };
  ushort* u_bf    = (ushort*)alloc((size_t)BL * CE_ * 2);
  ushort* vraw_bf = (ushort*)alloc((size_t)BL * CE_ * 2);   // reused as z_bf
  ushort* vs_bf   = (ushort*)alloc((size_t)BL * CE_ * 2);
  ushort* xn_bf   = (ushort*)alloc((size_t)BL * C_ * 2);
  float*  delta   = (float*)alloc((size_t)BL * CE_ * 4);
  float*  bc      = (float*)alloc((size_t)BL * 32 * 4);
  float*  S       = (float*)alloc((size_t)B_ * NCH * CE_ * NS * 4);
  float*  Dsum    = (float*)alloc((size_t)B_ * NCH * CE_ * 4);
  ushort* w_ex_bf = (ushort*)alloc((size_t)2 * CE_ * C_ * 2);
  ushort* w_pr_bf = (ushort*)alloc((size_t)C_ * CE_ * 2);
  ushort* wcat_bf = (ushort*)alloc((size_t)576 * CE_ * 2);
  float*  bcat    = (float*)alloc((size_t)576 * 4);
  ushort* z_bf = vraw_bf;

  prep_cast_k<<<1539, 256, 0, stream>>>(w_ex, w_proj, b_xp, W_dt, b_dt,
                                        w_ex_bf, w_pr_bf, bcat);
  wcat_k<<<1152, 256, 0, stream>>>(W_dt, W_xp, wcat_bf);
  ln_k<<<576, 256, 0, stream>>>(x, norm_w, norm_b, xn_bf);
  gemm_expand_k<<<dim3(16, 72), 256, 0, stream>>>(xn_bf, w_ex_bf, b_ex, u_bf, vraw_bf);
  dwconv_k<<<BL / 2, 256, 0, stream>>>(vraw_bf, dw_k, vs_bf);
  gemm_dbc_k<<<dim3(9, 72), 256, 0, stream>>>(vs_bf, wcat_bf, bcat, delta, bc);
  scan1_k<<<dim3(2, NCH, B_), 256, 0, stream>>>(delta, bc, vs_bf, A_log, S, Dsum);
  scan2_k<<<128, 256, 0, stream>>>(A_log, S, Dsum);
  scan3_k<<<dim3(2, NCH, B_), 256, 0, stream>>>(delta, bc, vs_bf, A_log, Dv, S, u_bf, z_bf);
  gemm_proj_k<<<dim3(4, 144), 256, 0, stream>>>(z_bf, w_pr_bf, b_proj, out);
}